// Round 17
// baseline (138.614 us; speedup 1.0000x reference)
//
#include <hip/hip_runtime.h>

typedef float f4 __attribute__((ext_vector_type(4)));
typedef float f2 __attribute__((ext_vector_type(2)));
typedef short short8 __attribute__((ext_vector_type(8)));
typedef float f32x4 __attribute__((ext_vector_type(4)));

#define NEG_INF -1e9f

__device__ inline void bsplit(float x, unsigned short& h, unsigned short& l) {
  union { float f; unsigned u; } a; a.f = x;
  unsigned rh = (a.u + 0x7fffu + ((a.u >> 16) & 1u)) >> 16;
  h = (unsigned short)rh;
  union { unsigned u; float f; } b; b.u = rh << 16;
  union { float f; unsigned u; } c; c.f = x - b.f;
  unsigned rl = (c.u + 0x7fffu + ((c.u >> 16) & 1u)) >> 16;
  l = (unsigned short)rl;
}

__device__ inline void gl_lds16(const void* g, void* l) {
  __builtin_amdgcn_global_load_lds(
      (const __attribute__((address_space(1))) unsigned int*)g,
      (__attribute__((address_space(3))) unsigned int*)l, 16, 0, 0);
}

// ---------------------------------------------------------------------------
// conv_aw (R8-exact)
// ---------------------------------------------------------------------------
__global__ __launch_bounds__(256) void conv_aw(
    const float* __restrict__ q, const float* __restrict__ v,
    const float* __restrict__ W1, const float* __restrict__ W2,
    unsigned short* __restrict__ Ahi, unsigned short* __restrict__ Alo,
    unsigned short* __restrict__ Whi, unsigned short* __restrict__ Wlo)
{
  __shared__ float ldsW[128][64];
  const int t = threadIdx.x;

  if (blockIdx.x < 512) {
    const int g = blockIdx.x * 256 + t;
    const int row64 = g & 63;
    const int panel = (g >> 6) & 31;
    const int kc    = g >> 11;
    const int rowg  = panel * 64 + row64;
    const float* src = (rowg < 1024) ? (q + (size_t)rowg * 512 + kc * 8)
                                     : (v + (size_t)(rowg - 1024) * 512 + kc * 8);
    f4 x0 = *reinterpret_cast<const f4*>(src);
    f4 x1 = *reinterpret_cast<const f4*>(src + 4);
    unsigned short h[8], l[8];
#pragma unroll
    for (int j = 0; j < 4; ++j) { bsplit(x0[j], h[j], l[j]); bsplit(x1[j], h[4+j], l[4+j]); }
    const size_t off = ((size_t)(panel * 64 + kc) * 64 + row64) * 8;
    short8 ph, pl;
#pragma unroll
    for (int j = 0; j < 8; ++j) { ph[j] = (short)h[j]; pl[j] = (short)l[j]; }
    *reinterpret_cast<short8*>(&Ahi[off]) = ph;
    *reinterpret_cast<short8*>(&Alo[off]) = pl;
    return;
  }

  const int bid   = blockIdx.x - 512;
  const int kslab = bid & 3;
  const int np    = (bid >> 2) & 7;
  const int z     = bid >> 5;
  const float* __restrict__ W = z ? W2 : W1;
  const int k0 = kslab * 128, n0 = np * 64;

#pragma unroll
  for (int it = 0; it < 8; ++it) {
    const int idx = it * 256 + t;
    const int kr  = idx >> 4;
    const int nc4 = (idx & 15) * 4;
    *reinterpret_cast<f4*>(&ldsW[kr][nc4]) =
        *reinterpret_cast<const f4*>(&W[(size_t)(k0 + kr) * 512 + n0 + nc4]);
  }
  __syncthreads();

  const int wpanel = z * 8 + np;
  const int n = t & 63;
#pragma unroll
  for (int it = 0; it < 4; ++it) {
    const int kcl = it * 4 + (t >> 6);
    short8 ph, pl;
#pragma unroll
    for (int j = 0; j < 8; ++j) {
      unsigned short h, l;
      bsplit(ldsW[kcl * 8 + j][n], h, l);
      ph[j] = (short)h; pl[j] = (short)l;
    }
    const size_t off = ((size_t)(wpanel * 64 + kslab * 16 + kcl) * 64 + n) * 8;
    *reinterpret_cast<short8*>(&Whi[off]) = ph;
    *reinterpret_cast<short8*>(&Wlo[off]) = pl;
  }
}

// ---------------------------------------------------------------------------
// projmm (R3-exact)
// ---------------------------------------------------------------------------
__global__ __launch_bounds__(256) void projmm(
    const unsigned short* __restrict__ Ahi, const unsigned short* __restrict__ Alo,
    const unsigned short* __restrict__ Whi, const unsigned short* __restrict__ Wlo,
    float* __restrict__ EQ, float* __restrict__ EKT)
{
  const int nb = blockIdx.x, mb = blockIdx.y, z = blockIdx.z;
  const int t = threadIdx.x;
  const int l = t & 63;
  const int w = t >> 6;
  const int wr = w >> 1, wc = w & 1;

  __shared__ __align__(16) short Ast[2][2][2048];
  __shared__ __align__(16) short Bst[2][2][2048];
  __shared__ float ldsT[64][67];

  const unsigned short* abase_h = Ahi + (size_t)(z * 16 + mb) * 32768;
  const unsigned short* abase_l = Alo + (size_t)(z * 16 + mb) * 32768;
  const unsigned short* wbase_h = Whi + (size_t)(z * 8 + nb) * 32768;
  const unsigned short* wbase_l = Wlo + (size_t)(z * 8 + nb) * 32768;

  const int ldst = (t >> 6) * 512;
  const int gsrc = t * 8;

#define STAGE(buf, ks)                                                        \
  do {                                                                        \
    gl_lds16(abase_h + (ks) * 2048 + gsrc, &Ast[buf][0][ldst]);               \
    gl_lds16(abase_l + (ks) * 2048 + gsrc, &Ast[buf][1][ldst]);               \
    gl_lds16(wbase_h + (ks) * 2048 + gsrc, &Bst[buf][0][ldst]);               \
    gl_lds16(wbase_l + (ks) * 2048 + gsrc, &Bst[buf][1][ldst]);               \
  } while (0)

  f32x4 acc[2][2] = {};
  STAGE(0, 0);
  __syncthreads();

  int buf = 0;
  for (int ks = 0; ks < 16; ++ks) {
    if (ks < 15) STAGE(buf ^ 1, ks + 1);
    const int kgo = (l >> 4) * 1024;
    short8 ah[2], al[2], bh[2], bl[2];
#pragma unroll
    for (int i = 0; i < 2; ++i) {
      const int ro = (wr * 32 + i * 16 + (l & 15)) * 16;
      ah[i] = *reinterpret_cast<const short8*>((const char*)&Ast[buf][0][0] + kgo + ro);
      al[i] = *reinterpret_cast<const short8*>((const char*)&Ast[buf][1][0] + kgo + ro);
    }
#pragma unroll
    for (int j = 0; j < 2; ++j) {
      const int co = (wc * 32 + j * 16 + (l & 15)) * 16;
      bh[j] = *reinterpret_cast<const short8*>((const char*)&Bst[buf][0][0] + kgo + co);
      bl[j] = *reinterpret_cast<const short8*>((const char*)&Bst[buf][1][0] + kgo + co);
    }
#pragma unroll
    for (int i = 0; i < 2; ++i)
#pragma unroll
      for (int j = 0; j < 2; ++j) {
        acc[i][j] = __builtin_amdgcn_mfma_f32_16x16x32_bf16(ah[i], bh[j], acc[i][j], 0, 0, 0);
        acc[i][j] = __builtin_amdgcn_mfma_f32_16x16x32_bf16(ah[i], bl[j], acc[i][j], 0, 0, 0);
        acc[i][j] = __builtin_amdgcn_mfma_f32_16x16x32_bf16(al[i], bh[j], acc[i][j], 0, 0, 0);
      }
    __syncthreads();
    buf ^= 1;
  }

  if (z == 0) {
#pragma unroll
    for (int i = 0; i < 2; ++i)
#pragma unroll
      for (int j = 0; j < 2; ++j)
#pragma unroll
        for (int r = 0; r < 4; ++r) {
          const int row = mb * 64 + wr * 32 + i * 16 + (l >> 4) * 4 + r;
          const int col = nb * 64 + wc * 32 + j * 16 + (l & 15);
          EQ[(size_t)row * 512 + col] = __expf(2.0f * acc[i][j][r]);
        }
  } else {
#pragma unroll
    for (int i = 0; i < 2; ++i)
#pragma unroll
      for (int j = 0; j < 2; ++j)
#pragma unroll
        for (int r = 0; r < 4; ++r) {
          const int rl = wr * 32 + i * 16 + (l >> 4) * 4 + r;
          const int cl = wc * 32 + j * 16 + (l & 15);
          ldsT[rl][cl] = __expf(2.0f * acc[i][j][r]);
        }
    __syncthreads();
    const int b  = (mb * 64) >> 8;
    const int v0 = (mb * 64) & 255;
    const int vl = t & 63;
#pragma unroll
    for (int it = 0; it < 16; ++it) {
      const int ul = it * 4 + (t >> 6);
      EKT[(size_t)b * 131072 + (size_t)(nb * 64 + ul) * 256 + v0 + vl] = ldsT[vl][ul];
    }
  }
#undef STAGE
}

// ---------------------------------------------------------------------------
// bah_attn — R15-EXACT with two idempotent measurement loops:
//   {B,C,D} x repsBCD   (reads stable partF; rewrites identical atT/attn_out)
//   {E,F}   x repsEF    (reads stable atT; rewrites identical ctxp/ctx_out)
// dur(attn) = base + (repsBCD-1)*BCD + (repsEF-1)*EF.
// ---------------------------------------------------------------------------
__global__ __launch_bounds__(1024) void bah_attn(
    const float* __restrict__ EQ, const float* __restrict__ EKT,
    const float* __restrict__ value, const int* __restrict__ mask,
    const float* __restrict__ scale,
    float* __restrict__ ctx_out, float* __restrict__ attn_out,
    int repsBCD, int repsEF)
{
  const int blk = blockIdx.x;
  const int b  = (blk & 7) >> 1;
  const int tg = (blk >> 3) + ((blk & 1) << 5);
  const int tq0 = tg * 4;
  const int bq  = b * 256 + tq0;

  const int tid = threadIdx.x;
  const int v4  = tid & 63;
  const int uq  = tid >> 6;
  const int w   = tid >> 6;
  const int l   = tid & 63;

  __shared__ f4    eq4s[512];
  __shared__ float ss[512];
  __shared__ float wredM[4][4];
  __shared__ float wredS[4][4];
  __shared__ float sumS_lds;
  __shared__ float atT[256][4];
  __shared__ __align__(16) char uA[131072];
  float* const ubufF = (float*)uA;
  float* const partF = (float*)uA;
  float* const ctxpF = (float*)(uA + 65536);

  const float* __restrict__ ekb = EKT + (size_t)b * (512 * 256);
  const float* __restrict__ eqb = EQ + (size_t)bq * 512;

  const int u0 = uq * 32;
  float* const wbase = ubufF + uq * 2048;

  const int r   = w & 3;
  const int vg  = w >> 2;
  const int v   = vg * 64 + l;

#define STAGEW(bufp, s)                                                       \
  do {                                                                        \
    _Pragma("unroll")                                                         \
    for (int c_ = 0; c_ < 4; ++c_)                                            \
      gl_lds16(ekb + (size_t)(u0 + (s) * 4 + c_) * 256 + l * 4,               \
               wbase + (bufp) * 1024 + c_ * 256);                             \
  } while (0)

  STAGEW(0, 0);

  const bool mok = (mask[b * 256 + v] != 0);

  {
    const int h  = tid >> 9;
    const int u2 = tid & 511;
    f2 e;
    e[0] = eqb[(size_t)(2 * h) * 512 + u2];
    e[1] = eqb[(size_t)(2 * h + 1) * 512 + u2];
    *(reinterpret_cast<f2*>(&eq4s[u2]) + h) = e;
    if (h == 0) ss[u2] = scale[u2];
  }
  __syncthreads();

  if (w == 0) {
    float s = 0.f;
#pragma unroll
    for (int j = 0; j < 8; ++j) s += ss[l + 64 * j];
#pragma unroll
    for (int off = 32; off; off >>= 1) s += __shfl_xor(s, off);
    if (l == 0) sumS_lds = s;
  }

  // ---- main loop (R15-exact) ----
  f2 accp[4][2] = {};
  int bufi = 0;
#pragma unroll 1
  for (int s = 0; s < 8; ++s) {
    if (s < 7) {
      STAGEW(bufi ^ 1, s + 1);
      asm volatile("s_waitcnt vmcnt(4)" ::: "memory");
    } else {
      asm volatile("s_waitcnt vmcnt(0)" ::: "memory");
    }
    __builtin_amdgcn_sched_barrier(0);
    const float* bp = wbase + bufi * 1024;
#pragma unroll
    for (int cp = 0; cp < 2; ++cp) {
      const int uA_ = u0 + s * 4 + 2 * cp;
      const f4 ekA4 = *reinterpret_cast<const f4*>(bp + (2 * cp) * 256 + v4 * 4);
      const f4 ekB4 = *reinterpret_cast<const f4*>(bp + (2 * cp + 1) * 256 + v4 * 4);
      const f2 ekA[2] = {{ekA4[0], ekA4[1]}, {ekA4[2], ekA4[3]}};
      const f2 ekB[2] = {{ekB4[0], ekB4[1]}, {ekB4[2], ekB4[3]}};
      const f4 eqA = eq4s[uA_];
      const f4 eqB = eq4s[uA_ + 1];
      const f2 sp  = *reinterpret_cast<const f2*>(&ss[uA_]);
      const f2 sA2 = {sp[0], sp[0]};
      const f2 sB2 = {sp[1], sp[1]};
      const f2 one2 = {1.0f, 1.0f};
#pragma unroll
      for (int i = 0; i < 4; ++i) {
        const f2 eA2 = {eqA[i], eqA[i]};
        const f2 eB2 = {eqB[i], eqB[i]};
#pragma unroll
        for (int jh = 0; jh < 2; ++jh) {
          const f2 dA  = __builtin_elementwise_fma(eA2, ekA[jh], one2);
          const f2 dB  = __builtin_elementwise_fma(eB2, ekB[jh], one2);
          const f2 num = __builtin_elementwise_fma(sA2, dB, sB2 * dA);
          const f2 P   = dA * dB;
          f2 r_;
          r_[0] = __builtin_amdgcn_rcpf(P[0]);
          r_[1] = __builtin_amdgcn_rcpf(P[1]);
          accp[i][jh] = __builtin_elementwise_fma(num, r_, accp[i][jh]);
        }
      }
    }
    bufi ^= 1;
  }

  // ---- Phase A ----
#pragma unroll
  for (int i = 0; i < 4; ++i) {
    const f4 a4 = {accp[i][0][0], accp[i][0][1], accp[i][1][0], accp[i][1][1]};
    *reinterpret_cast<f4*>(partF + uq * 2048 + i * 256 + v4 * 4) = a4;
  }
  __syncthreads();

  // ==== MEASUREMENT LOOP 1: {B,C,D} x repsBCD (idempotent) ====
  float sc, ex;
  for (int rb = 0; rb < repsBCD; ++rb) {
    {
      float p = 0.f;
#pragma unroll
      for (int u2 = 0; u2 < 16; ++u2) p += partF[u2 * 2048 + r * 256 + v];
      sc = mok ? (sumS_lds - 2.0f * p) : NEG_INF;
      float m = sc;
#pragma unroll
      for (int off = 32; off; off >>= 1) m = fmaxf(m, __shfl_xor(m, off));
      if (l == 0) wredM[r][vg] = m;
    }
    __syncthreads();
    {
      const float m = fmaxf(fmaxf(wredM[r][0], wredM[r][1]),
                            fmaxf(wredM[r][2], wredM[r][3]));
      ex = __expf(sc - m);
      float sm = ex;
#pragma unroll
      for (int off = 32; off; off >>= 1) sm += __shfl_xor(sm, off);
      if (l == 0) wredS[r][vg] = sm;
    }
    __syncthreads();
    {
      const float denom = (wredS[r][0] + wredS[r][1]) + (wredS[r][2] + wredS[r][3]);
      const float a = ex * __builtin_amdgcn_rcpf(denom);
      atT[v][r] = a;
      attn_out[(size_t)(bq + r) * 256 + v] = a;
    }
    __syncthreads();
  }

  // ==== MEASUREMENT LOOP 2: {E,F} x repsEF (idempotent) ====
  const int vc8 = w & 7;
  const int dh  = w >> 3;
  const float* __restrict__ vb = value + (size_t)b * (256 * 512) + dh * 256;
  for (int re = 0; re < repsEF; ++re) {
    f4 g0 = {0,0,0,0}, g1 = {0,0,0,0}, g2 = {0,0,0,0}, g3 = {0,0,0,0};
#pragma unroll 4
    for (int v2 = 0; v2 < 32; ++v2) {
      const int vv = vc8 * 32 + v2;
      const f4 a4 = *reinterpret_cast<const f4*>(&atT[vv][0]);
      const f4 x  = *reinterpret_cast<const f4*>(&vb[(size_t)vv * 512 + l * 4]);
      g0 += a4[0] * x;
      g1 += a4[1] * x;
      g2 += a4[2] * x;
      g3 += a4[3] * x;
    }
    {
      float* const cp = ctxpF + vc8 * 2048 + dh * 256 + l * 4;
      *reinterpret_cast<f4*>(cp + 0 * 512) = g0;
      *reinterpret_cast<f4*>(cp + 1 * 512) = g1;
      *reinterpret_cast<f4*>(cp + 2 * 512) = g2;
      *reinterpret_cast<f4*>(cp + 3 * 512) = g3;
    }
    __syncthreads();
    {
      const int row = tid >> 8;
      const int d2  = (tid & 255) * 2;
      f2 s = {0.f, 0.f};
#pragma unroll
      for (int vc = 0; vc < 8; ++vc)
        s += *reinterpret_cast<const f2*>(ctxpF + vc * 2048 + row * 512 + d2);
      *reinterpret_cast<f2*>(&ctx_out[(size_t)(bq + row) * 512 + d2]) = s;
    }
    __syncthreads();
  }
#undef STAGEW
}

// ---------------------------------------------------------------------------
extern "C" void kernel_launch(void* const* d_in, const int* in_sizes, int n_in,
                              void* d_out, int out_size, void* d_ws, size_t ws_size,
                              hipStream_t stream) {
  const float* query = (const float*)d_in[0];
  const float* value = (const float*)d_in[1];
  const int*   mask  = (const int*)d_in[2];
  const float* W1    = (const float*)d_in[3];
  const float* W2    = (const float*)d_in[4];
  const float* scale = (const float*)d_in[5];

  char* ws = (char*)d_ws;
  float* EQ  = (float*)(ws);                         // 2 MB
  float* EKT = (float*)(ws + (2u << 20));            // 2 MB
  unsigned short* Ahi = (unsigned short*)(ws + (4u << 20));   // 2 MB
  unsigned short* Alo = (unsigned short*)(ws + (6u << 20));   // 2 MB
  unsigned short* Whi = (unsigned short*)(ws + (8u << 20));   // 1 MB
  unsigned short* Wlo = (unsigned short*)(ws + (9u << 20));   // 1 MB

  float* ctx  = (float*)d_out;
  float* attn = ctx + 4 * 256 * 512;

  conv_aw<<<dim3(576), 256, 0, stream>>>(query, value, W1, W2, Ahi, Alo, Whi, Wlo);
  projmm<<<dim3(8, 16, 2), 256, 0, stream>>>(Ahi, Alo, Whi, Wlo, EQ, EKT);
  // MEASUREMENT: epilogue phases repeated 16x each (idempotent).
  // dur(attn) = base + 15*BCD + 15*EF -> decides phases-vs-residual.
  bah_attn<<<dim3(256), 1024, 0, stream>>>(EQ, EKT, value, mask, scale, ctx, attn,
                                           16, 16);
}

// Round 18
// 42.809 us; speedup vs baseline: 3.2380x; 3.2380x over previous
//
#include <hip/hip_runtime.h>

typedef float f4 __attribute__((ext_vector_type(4)));
typedef float f2 __attribute__((ext_vector_type(2)));
typedef short short8 __attribute__((ext_vector_type(8)));
typedef float f32x4 __attribute__((ext_vector_type(4)));

#define NEG_INF -1e9f

__device__ inline void bsplit(float x, unsigned short& h, unsigned short& l) {
  union { float f; unsigned u; } a; a.f = x;
  unsigned rh = (a.u + 0x7fffu + ((a.u >> 16) & 1u)) >> 16;
  h = (unsigned short)rh;
  union { unsigned u; float f; } b; b.u = rh << 16;
  union { float f; unsigned u; } c; c.f = x - b.f;
  unsigned rl = (c.u + 0x7fffu + ((c.u >> 16) & 1u)) >> 16;
  l = (unsigned short)rl;
}

__device__ inline void gl_lds16(const void* g, void* l) {
  __builtin_amdgcn_global_load_lds(
      (const __attribute__((address_space(1))) unsigned int*)g,
      (__attribute__((address_space(3))) unsigned int*)l, 16, 0, 0);
}

// ---------------------------------------------------------------------------
// conv_aw (R8-exact)
// ---------------------------------------------------------------------------
__global__ __launch_bounds__(256) void conv_aw(
    const float* __restrict__ q, const float* __restrict__ v,
    const float* __restrict__ W1, const float* __restrict__ W2,
    unsigned short* __restrict__ Ahi, unsigned short* __restrict__ Alo,
    unsigned short* __restrict__ Whi, unsigned short* __restrict__ Wlo)
{
  __shared__ float ldsW[128][64];
  const int t = threadIdx.x;

  if (blockIdx.x < 512) {
    const int g = blockIdx.x * 256 + t;
    const int row64 = g & 63;
    const int panel = (g >> 6) & 31;
    const int kc    = g >> 11;
    const int rowg  = panel * 64 + row64;
    const float* src = (rowg < 1024) ? (q + (size_t)rowg * 512 + kc * 8)
                                     : (v + (size_t)(rowg - 1024) * 512 + kc * 8);
    f4 x0 = *reinterpret_cast<const f4*>(src);
    f4 x1 = *reinterpret_cast<const f4*>(src + 4);
    unsigned short h[8], l[8];
#pragma unroll
    for (int j = 0; j < 4; ++j) { bsplit(x0[j], h[j], l[j]); bsplit(x1[j], h[4+j], l[4+j]); }
    const size_t off = ((size_t)(panel * 64 + kc) * 64 + row64) * 8;
    short8 ph, pl;
#pragma unroll
    for (int j = 0; j < 8; ++j) { ph[j] = (short)h[j]; pl[j] = (short)l[j]; }
    *reinterpret_cast<short8*>(&Ahi[off]) = ph;
    *reinterpret_cast<short8*>(&Alo[off]) = pl;
    return;
  }

  const int bid   = blockIdx.x - 512;
  const int kslab = bid & 3;
  const int np    = (bid >> 2) & 7;
  const int z     = bid >> 5;
  const float* __restrict__ W = z ? W2 : W1;
  const int k0 = kslab * 128, n0 = np * 64;

#pragma unroll
  for (int it = 0; it < 8; ++it) {
    const int idx = it * 256 + t;
    const int kr  = idx >> 4;
    const int nc4 = (idx & 15) * 4;
    *reinterpret_cast<f4*>(&ldsW[kr][nc4]) =
        *reinterpret_cast<const f4*>(&W[(size_t)(k0 + kr) * 512 + n0 + nc4]);
  }
  __syncthreads();

  const int wpanel = z * 8 + np;
  const int n = t & 63;
#pragma unroll
  for (int it = 0; it < 4; ++it) {
    const int kcl = it * 4 + (t >> 6);
    short8 ph, pl;
#pragma unroll
    for (int j = 0; j < 8; ++j) {
      unsigned short h, l;
      bsplit(ldsW[kcl * 8 + j][n], h, l);
      ph[j] = (short)h; pl[j] = (short)l;
    }
    const size_t off = ((size_t)(wpanel * 64 + kslab * 16 + kcl) * 64 + n) * 8;
    *reinterpret_cast<short8*>(&Whi[off]) = ph;
    *reinterpret_cast<short8*>(&Wlo[off]) = pl;
  }
}

// ---------------------------------------------------------------------------
// projmm v2: split-K over 2 sub-groups (512 thr). sg owns 8 of 16 K-steps on
// its own LDS double-buffer; sg1's acc -> lane-contiguous f32x4 LDS; sg0 adds
// and runs the verified epilogue. Serial depth 16 -> 8 barriered steps.
// ---------------------------------------------------------------------------
__global__ __launch_bounds__(512) void projmm(
    const unsigned short* __restrict__ Ahi, const unsigned short* __restrict__ Alo,
    const unsigned short* __restrict__ Whi, const unsigned short* __restrict__ Wlo,
    float* __restrict__ EQ, float* __restrict__ EKT)
{
  const int nb = blockIdx.x, mb = blockIdx.y, z = blockIdx.z;
  const int tid = threadIdx.x;
  const int sg = tid >> 8;          // K-half
  const int t  = tid & 255;
  const int l  = t & 63;
  const int w  = t >> 6;
  const int wr = w >> 1, wc = w & 1;

  __shared__ __align__(16) short Ast[2][2][2][2048];  // [sg][buf][hi/lo]
  __shared__ __align__(16) short Bst[2][2][2][2048];
  __shared__ __align__(16) f32x4 red4[4][256];        // 16 KB, lane-contiguous
  __shared__ float ldsT[64][67];

  const unsigned short* abase_h = Ahi + (size_t)(z * 16 + mb) * 32768;
  const unsigned short* abase_l = Alo + (size_t)(z * 16 + mb) * 32768;
  const unsigned short* wbase_h = Whi + (size_t)(z * 8 + nb) * 32768;
  const unsigned short* wbase_l = Wlo + (size_t)(z * 8 + nb) * 32768;

  const int ldst = w * 512;         // wave-uniform LDS dest base (shorts)
  const int gsrc = t * 8;           // per-lane global offset (shorts)

#define STAGE(buf, ks)                                                        \
  do {                                                                        \
    gl_lds16(abase_h + (ks) * 2048 + gsrc, &Ast[sg][buf][0][ldst]);           \
    gl_lds16(abase_l + (ks) * 2048 + gsrc, &Ast[sg][buf][1][ldst]);           \
    gl_lds16(wbase_h + (ks) * 2048 + gsrc, &Bst[sg][buf][0][ldst]);           \
    gl_lds16(wbase_l + (ks) * 2048 + gsrc, &Bst[sg][buf][1][ldst]);           \
  } while (0)

  f32x4 acc[2][2] = {};
  const int ks0 = sg * 8;
  STAGE(0, ks0);
  __syncthreads();

  int buf = 0;
#pragma unroll 1
  for (int kl = 0; kl < 8; ++kl) {
    if (kl < 7) STAGE(buf ^ 1, ks0 + kl + 1);
    const int kgo = (l >> 4) * 1024;
    short8 ah[2], al[2], bh[2], bl[2];
#pragma unroll
    for (int i = 0; i < 2; ++i) {
      const int ro = (wr * 32 + i * 16 + (l & 15)) * 16;
      ah[i] = *reinterpret_cast<const short8*>((const char*)&Ast[sg][buf][0][0] + kgo + ro);
      al[i] = *reinterpret_cast<const short8*>((const char*)&Ast[sg][buf][1][0] + kgo + ro);
    }
#pragma unroll
    for (int j = 0; j < 2; ++j) {
      const int co = (wc * 32 + j * 16 + (l & 15)) * 16;
      bh[j] = *reinterpret_cast<const short8*>((const char*)&Bst[sg][buf][0][0] + kgo + co);
      bl[j] = *reinterpret_cast<const short8*>((const char*)&Bst[sg][buf][1][0] + kgo + co);
    }
#pragma unroll
    for (int i = 0; i < 2; ++i)
#pragma unroll
      for (int j = 0; j < 2; ++j) {
        acc[i][j] = __builtin_amdgcn_mfma_f32_16x16x32_bf16(ah[i], bh[j], acc[i][j], 0, 0, 0);
        acc[i][j] = __builtin_amdgcn_mfma_f32_16x16x32_bf16(ah[i], bl[j], acc[i][j], 0, 0, 0);
        acc[i][j] = __builtin_amdgcn_mfma_f32_16x16x32_bf16(al[i], bh[j], acc[i][j], 0, 0, 0);
      }
    __syncthreads();
    buf ^= 1;
  }

  // split-K reduce: sg1 -> LDS (b128, lane-contiguous), sg0 adds.
  if (sg == 1) {
#pragma unroll
    for (int i = 0; i < 2; ++i)
#pragma unroll
      for (int j = 0; j < 2; ++j)
        red4[i * 2 + j][t] = acc[i][j];
  }
  __syncthreads();

  if (z == 0) {
    if (sg == 0) {
#pragma unroll
      for (int i = 0; i < 2; ++i)
#pragma unroll
        for (int j = 0; j < 2; ++j) {
          const f32x4 o = red4[i * 2 + j][t];
          const f32x4 s = acc[i][j] + o;
#pragma unroll
          for (int r = 0; r < 4; ++r) {
            const int row = mb * 64 + wr * 32 + i * 16 + (l >> 4) * 4 + r;
            const int col = nb * 64 + wc * 32 + j * 16 + (l & 15);
            EQ[(size_t)row * 512 + col] = __expf(2.0f * s[r]);
          }
        }
    }
  } else {
    if (sg == 0) {
#pragma unroll
      for (int i = 0; i < 2; ++i)
#pragma unroll
        for (int j = 0; j < 2; ++j) {
          const f32x4 o = red4[i * 2 + j][t];
          const f32x4 s = acc[i][j] + o;
#pragma unroll
          for (int r = 0; r < 4; ++r) {
            const int rl = wr * 32 + i * 16 + (l >> 4) * 4 + r;
            const int cl = wc * 32 + j * 16 + (l & 15);
            ldsT[rl][cl] = __expf(2.0f * s[r]);
          }
        }
    }
    __syncthreads();
    const int b  = (mb * 64) >> 8;
    const int v0 = (mb * 64) & 255;
    const int vl = tid & 63;
#pragma unroll
    for (int it = 0; it < 8; ++it) {
      const int ul = it * 8 + (tid >> 6);
      EKT[(size_t)b * 131072 + (size_t)(nb * 64 + ul) * 256 + v0 + vl] = ldsT[vl][ul];
    }
  }
#undef STAGE
}

// ---------------------------------------------------------------------------
// bah_attn — R15-EXACT (best verified: 46.76 us total).
// ---------------------------------------------------------------------------
__global__ __launch_bounds__(1024) void bah_attn(
    const float* __restrict__ EQ, const float* __restrict__ EKT,
    const float* __restrict__ value, const int* __restrict__ mask,
    const float* __restrict__ scale,
    float* __restrict__ ctx_out, float* __restrict__ attn_out)
{
  const int blk = blockIdx.x;
  const int b  = (blk & 7) >> 1;
  const int tg = (blk >> 3) + ((blk & 1) << 5);
  const int tq0 = tg * 4;
  const int bq  = b * 256 + tq0;

  const int tid = threadIdx.x;
  const int v4  = tid & 63;
  const int uq  = tid >> 6;
  const int w   = tid >> 6;
  const int l   = tid & 63;

  __shared__ f4    eq4s[512];
  __shared__ float ss[512];
  __shared__ float wredM[4][4];
  __shared__ float wredS[4][4];
  __shared__ float sumS_lds;
  __shared__ float atT[256][4];
  __shared__ __align__(16) char uA[131072];
  float* const ubufF = (float*)uA;
  float* const partF = (float*)uA;
  float* const ctxpF = (float*)(uA + 65536);

  const float* __restrict__ ekb = EKT + (size_t)b * (512 * 256);
  const float* __restrict__ eqb = EQ + (size_t)bq * 512;

  const int u0 = uq * 32;
  float* const wbase = ubufF + uq * 2048;

  const int r   = w & 3;
  const int vg  = w >> 2;
  const int v   = vg * 64 + l;

#define STAGEW(bufp, s)                                                       \
  do {                                                                        \
    _Pragma("unroll")                                                         \
    for (int c_ = 0; c_ < 4; ++c_)                                            \
      gl_lds16(ekb + (size_t)(u0 + (s) * 4 + c_) * 256 + l * 4,               \
               wbase + (bufp) * 1024 + c_ * 256);                             \
  } while (0)

  STAGEW(0, 0);

  const bool mok = (mask[b * 256 + v] != 0);

  {
    const int h  = tid >> 9;
    const int u2 = tid & 511;
    f2 e;
    e[0] = eqb[(size_t)(2 * h) * 512 + u2];
    e[1] = eqb[(size_t)(2 * h + 1) * 512 + u2];
    *(reinterpret_cast<f2*>(&eq4s[u2]) + h) = e;
    if (h == 0) ss[u2] = scale[u2];
  }
  __syncthreads();

  if (w == 0) {
    float s = 0.f;
#pragma unroll
    for (int j = 0; j < 8; ++j) s += ss[l + 64 * j];
#pragma unroll
    for (int off = 32; off; off >>= 1) s += __shfl_xor(s, off);
    if (l == 0) sumS_lds = s;
  }

  f2 accp[4][2] = {};
  int bufi = 0;
#pragma unroll 1
  for (int s = 0; s < 8; ++s) {
    if (s < 7) {
      STAGEW(bufi ^ 1, s + 1);
      asm volatile("s_waitcnt vmcnt(4)" ::: "memory");
    } else {
      asm volatile("s_waitcnt vmcnt(0)" ::: "memory");
    }
    __builtin_amdgcn_sched_barrier(0);
    const float* bp = wbase + bufi * 1024;
#pragma unroll
    for (int cp = 0; cp < 2; ++cp) {
      const int uA_ = u0 + s * 4 + 2 * cp;
      const f4 ekA4 = *reinterpret_cast<const f4*>(bp + (2 * cp) * 256 + v4 * 4);
      const f4 ekB4 = *reinterpret_cast<const f4*>(bp + (2 * cp + 1) * 256 + v4 * 4);
      const f2 ekA[2] = {{ekA4[0], ekA4[1]}, {ekA4[2], ekA4[3]}};
      const f2 ekB[2] = {{ekB4[0], ekB4[1]}, {ekB4[2], ekB4[3]}};
      const f4 eqA = eq4s[uA_];
      const f4 eqB = eq4s[uA_ + 1];
      const f2 sp  = *reinterpret_cast<const f2*>(&ss[uA_]);
      const f2 sA2 = {sp[0], sp[0]};
      const f2 sB2 = {sp[1], sp[1]};
      const f2 one2 = {1.0f, 1.0f};
#pragma unroll
      for (int i = 0; i < 4; ++i) {
        const f2 eA2 = {eqA[i], eqA[i]};
        const f2 eB2 = {eqB[i], eqB[i]};
#pragma unroll
        for (int jh = 0; jh < 2; ++jh) {
          const f2 dA  = __builtin_elementwise_fma(eA2, ekA[jh], one2);
          const f2 dB  = __builtin_elementwise_fma(eB2, ekB[jh], one2);
          const f2 num = __builtin_elementwise_fma(sA2, dB, sB2 * dA);
          const f2 P   = dA * dB;
          f2 r_;
          r_[0] = __builtin_amdgcn_rcpf(P[0]);
          r_[1] = __builtin_amdgcn_rcpf(P[1]);
          accp[i][jh] = __builtin_elementwise_fma(num, r_, accp[i][jh]);
        }
      }
    }
    bufi ^= 1;
  }

#pragma unroll
  for (int i = 0; i < 4; ++i) {
    const f4 a4 = {accp[i][0][0], accp[i][0][1], accp[i][1][0], accp[i][1][1]};
    *reinterpret_cast<f4*>(partF + uq * 2048 + i * 256 + v4 * 4) = a4;
  }
  __syncthreads();

  float sc, ex;
  {
    float p = 0.f;
#pragma unroll
    for (int u2 = 0; u2 < 16; ++u2) p += partF[u2 * 2048 + r * 256 + v];
    sc = mok ? (sumS_lds - 2.0f * p) : NEG_INF;
    float m = sc;
#pragma unroll
    for (int off = 32; off; off >>= 1) m = fmaxf(m, __shfl_xor(m, off));
    if (l == 0) wredM[r][vg] = m;
  }
  __syncthreads();

  {
    const float m = fmaxf(fmaxf(wredM[r][0], wredM[r][1]),
                          fmaxf(wredM[r][2], wredM[r][3]));
    ex = __expf(sc - m);
    float sm = ex;
#pragma unroll
    for (int off = 32; off; off >>= 1) sm += __shfl_xor(sm, off);
    if (l == 0) wredS[r][vg] = sm;
  }
  __syncthreads();

  {
    const float denom = (wredS[r][0] + wredS[r][1]) + (wredS[r][2] + wredS[r][3]);
    const float a = ex * __builtin_amdgcn_rcpf(denom);
    atT[v][r] = a;
    attn_out[(size_t)(bq + r) * 256 + v] = a;
  }
  __syncthreads();

  const int vc8 = w & 7;
  const int dh  = w >> 3;
  const float* __restrict__ vb = value + (size_t)b * (256 * 512) + dh * 256;
  f4 g0 = {0,0,0,0}, g1 = {0,0,0,0}, g2 = {0,0,0,0}, g3 = {0,0,0,0};
#pragma unroll 4
  for (int v2 = 0; v2 < 32; ++v2) {
    const int vv = vc8 * 32 + v2;
    const f4 a4 = *reinterpret_cast<const f4*>(&atT[vv][0]);
    const f4 x  = *reinterpret_cast<const f4*>(&vb[(size_t)vv * 512 + l * 4]);
    g0 += a4[0] * x;
    g1 += a4[1] * x;
    g2 += a4[2] * x;
    g3 += a4[3] * x;
  }
  {
    float* const cp = ctxpF + vc8 * 2048 + dh * 256 + l * 4;
    *reinterpret_cast<f4*>(cp + 0 * 512) = g0;
    *reinterpret_cast<f4*>(cp + 1 * 512) = g1;
    *reinterpret_cast<f4*>(cp + 2 * 512) = g2;
    *reinterpret_cast<f4*>(cp + 3 * 512) = g3;
  }
  __syncthreads();

  {
    const int row = tid >> 8;
    const int d2  = (tid & 255) * 2;
    f2 s = {0.f, 0.f};
#pragma unroll
    for (int vc = 0; vc < 8; ++vc)
      s += *reinterpret_cast<const f2*>(ctxpF + vc * 2048 + row * 512 + d2);
    *reinterpret_cast<f2*>(&ctx_out[(size_t)(bq + row) * 512 + d2]) = s;
  }
#undef STAGEW
}

// ---------------------------------------------------------------------------
extern "C" void kernel_launch(void* const* d_in, const int* in_sizes, int n_in,
                              void* d_out, int out_size, void* d_ws, size_t ws_size,
                              hipStream_t stream) {
  const float* query = (const float*)d_in[0];
  const float* value = (const float*)d_in[1];
  const int*   mask  = (const int*)d_in[2];
  const float* W1    = (const float*)d_in[3];
  const float* W2    = (const float*)d_in[4];
  const float* scale = (const float*)d_in[5];

  char* ws = (char*)d_ws;
  float* EQ  = (float*)(ws);                         // 2 MB
  float* EKT = (float*)(ws + (2u << 20));            // 2 MB
  unsigned short* Ahi = (unsigned short*)(ws + (4u << 20));   // 2 MB
  unsigned short* Alo = (unsigned short*)(ws + (6u << 20));   // 2 MB
  unsigned short* Whi = (unsigned short*)(ws + (8u << 20));   // 1 MB
  unsigned short* Wlo = (unsigned short*)(ws + (9u << 20));   // 1 MB

  float* ctx  = (float*)d_out;
  float* attn = ctx + 4 * 256 * 512;

  conv_aw<<<dim3(576), 256, 0, stream>>>(query, value, W1, W2, Ahi, Alo, Whi, Wlo);
  projmm<<<dim3(8, 16, 2), 512, 0, stream>>>(Ahi, Alo, Whi, Wlo, EQ, EKT);
  bah_attn<<<dim3(256), 1024, 0, stream>>>(EQ, EKT, value, mask, scale, ctx, attn);
}

// Round 19
// 41.951 us; speedup vs baseline: 3.3042x; 1.0205x over previous
//
#include <hip/hip_runtime.h>

typedef float f4 __attribute__((ext_vector_type(4)));
typedef float f2 __attribute__((ext_vector_type(2)));
typedef short short8 __attribute__((ext_vector_type(8)));
typedef float f32x4 __attribute__((ext_vector_type(4)));

#define NEG_INF -1e9f

__device__ inline void bsplit(float x, unsigned short& h, unsigned short& l) {
  union { float f; unsigned u; } a; a.f = x;
  unsigned rh = (a.u + 0x7fffu + ((a.u >> 16) & 1u)) >> 16;
  h = (unsigned short)rh;
  union { unsigned u; float f; } b; b.u = rh << 16;
  union { float f; unsigned u; } c; c.f = x - b.f;
  unsigned rl = (c.u + 0x7fffu + ((c.u >> 16) & 1u)) >> 16;
  l = (unsigned short)rl;
}

__device__ inline void gl_lds16(const void* g, void* l) {
  __builtin_amdgcn_global_load_lds(
      (const __attribute__((address_space(1))) unsigned int*)g,
      (__attribute__((address_space(3))) unsigned int*)l, 16, 0, 0);
}

// ---------------------------------------------------------------------------
// conv_aw (R8-exact)
// ---------------------------------------------------------------------------
__global__ __launch_bounds__(256) void conv_aw(
    const float* __restrict__ q, const float* __restrict__ v,
    const float* __restrict__ W1, const float* __restrict__ W2,
    unsigned short* __restrict__ Ahi, unsigned short* __restrict__ Alo,
    unsigned short* __restrict__ Whi, unsigned short* __restrict__ Wlo)
{
  __shared__ float ldsW[128][64];
  const int t = threadIdx.x;

  if (blockIdx.x < 512) {
    const int g = blockIdx.x * 256 + t;
    const int row64 = g & 63;
    const int panel = (g >> 6) & 31;
    const int kc    = g >> 11;
    const int rowg  = panel * 64 + row64;
    const float* src = (rowg < 1024) ? (q + (size_t)rowg * 512 + kc * 8)
                                     : (v + (size_t)(rowg - 1024) * 512 + kc * 8);
    f4 x0 = *reinterpret_cast<const f4*>(src);
    f4 x1 = *reinterpret_cast<const f4*>(src + 4);
    unsigned short h[8], l[8];
#pragma unroll
    for (int j = 0; j < 4; ++j) { bsplit(x0[j], h[j], l[j]); bsplit(x1[j], h[4+j], l[4+j]); }
    const size_t off = ((size_t)(panel * 64 + kc) * 64 + row64) * 8;
    short8 ph, pl;
#pragma unroll
    for (int j = 0; j < 8; ++j) { ph[j] = (short)h[j]; pl[j] = (short)l[j]; }
    *reinterpret_cast<short8*>(&Ahi[off]) = ph;
    *reinterpret_cast<short8*>(&Alo[off]) = pl;
    return;
  }

  const int bid   = blockIdx.x - 512;
  const int kslab = bid & 3;
  const int np    = (bid >> 2) & 7;
  const int z     = bid >> 5;
  const float* __restrict__ W = z ? W2 : W1;
  const int k0 = kslab * 128, n0 = np * 64;

#pragma unroll
  for (int it = 0; it < 8; ++it) {
    const int idx = it * 256 + t;
    const int kr  = idx >> 4;
    const int nc4 = (idx & 15) * 4;
    *reinterpret_cast<f4*>(&ldsW[kr][nc4]) =
        *reinterpret_cast<const f4*>(&W[(size_t)(k0 + kr) * 512 + n0 + nc4]);
  }
  __syncthreads();

  const int wpanel = z * 8 + np;
  const int n = t & 63;
#pragma unroll
  for (int it = 0; it < 4; ++it) {
    const int kcl = it * 4 + (t >> 6);
    short8 ph, pl;
#pragma unroll
    for (int j = 0; j < 8; ++j) {
      unsigned short h, l;
      bsplit(ldsW[kcl * 8 + j][n], h, l);
      ph[j] = (short)h; pl[j] = (short)l;
    }
    const size_t off = ((size_t)(wpanel * 64 + kslab * 16 + kcl) * 64 + n) * 8;
    *reinterpret_cast<short8*>(&Whi[off]) = ph;
    *reinterpret_cast<short8*>(&Wlo[off]) = pl;
  }
}

// ---------------------------------------------------------------------------
// projmm v3: split-K (R18) + z=0 now stores EQT4[tg][r][u] transposed-packed
// (coalesced via ldsT) for attn's scalar-path eq loads. EQ buffer dropped.
// ---------------------------------------------------------------------------
__global__ __launch_bounds__(512) void projmm(
    const unsigned short* __restrict__ Ahi, const unsigned short* __restrict__ Alo,
    const unsigned short* __restrict__ Whi, const unsigned short* __restrict__ Wlo,
    float* __restrict__ EQT4, float* __restrict__ EKT)
{
  const int nb = blockIdx.x, mb = blockIdx.y, z = blockIdx.z;
  const int tid = threadIdx.x;
  const int sg = tid >> 8;
  const int t  = tid & 255;
  const int l  = t & 63;
  const int w  = t >> 6;
  const int wr = w >> 1, wc = w & 1;

  __shared__ __align__(16) short Ast[2][2][2][2048];
  __shared__ __align__(16) short Bst[2][2][2][2048];
  __shared__ __align__(16) f32x4 red4[4][256];
  __shared__ float ldsT[64][67];

  const unsigned short* abase_h = Ahi + (size_t)(z * 16 + mb) * 32768;
  const unsigned short* abase_l = Alo + (size_t)(z * 16 + mb) * 32768;
  const unsigned short* wbase_h = Whi + (size_t)(z * 8 + nb) * 32768;
  const unsigned short* wbase_l = Wlo + (size_t)(z * 8 + nb) * 32768;

  const int ldst = w * 512;
  const int gsrc = t * 8;

#define STAGE(buf, ks)                                                        \
  do {                                                                        \
    gl_lds16(abase_h + (ks) * 2048 + gsrc, &Ast[sg][buf][0][ldst]);           \
    gl_lds16(abase_l + (ks) * 2048 + gsrc, &Ast[sg][buf][1][ldst]);           \
    gl_lds16(wbase_h + (ks) * 2048 + gsrc, &Bst[sg][buf][0][ldst]);           \
    gl_lds16(wbase_l + (ks) * 2048 + gsrc, &Bst[sg][buf][1][ldst]);           \
  } while (0)

  f32x4 acc[2][2] = {};
  const int ks0 = sg * 8;
  STAGE(0, ks0);
  __syncthreads();

  int buf = 0;
#pragma unroll 1
  for (int kl = 0; kl < 8; ++kl) {
    if (kl < 7) STAGE(buf ^ 1, ks0 + kl + 1);
    const int kgo = (l >> 4) * 1024;
    short8 ah[2], al[2], bh[2], bl[2];
#pragma unroll
    for (int i = 0; i < 2; ++i) {
      const int ro = (wr * 32 + i * 16 + (l & 15)) * 16;
      ah[i] = *reinterpret_cast<const short8*>((const char*)&Ast[sg][buf][0][0] + kgo + ro);
      al[i] = *reinterpret_cast<const short8*>((const char*)&Ast[sg][buf][1][0] + kgo + ro);
    }
#pragma unroll
    for (int j = 0; j < 2; ++j) {
      const int co = (wc * 32 + j * 16 + (l & 15)) * 16;
      bh[j] = *reinterpret_cast<const short8*>((const char*)&Bst[sg][buf][0][0] + kgo + co);
      bl[j] = *reinterpret_cast<const short8*>((const char*)&Bst[sg][buf][1][0] + kgo + co);
    }
#pragma unroll
    for (int i = 0; i < 2; ++i)
#pragma unroll
      for (int j = 0; j < 2; ++j) {
        acc[i][j] = __builtin_amdgcn_mfma_f32_16x16x32_bf16(ah[i], bh[j], acc[i][j], 0, 0, 0);
        acc[i][j] = __builtin_amdgcn_mfma_f32_16x16x32_bf16(ah[i], bl[j], acc[i][j], 0, 0, 0);
        acc[i][j] = __builtin_amdgcn_mfma_f32_16x16x32_bf16(al[i], bh[j], acc[i][j], 0, 0, 0);
      }
    __syncthreads();
    buf ^= 1;
  }

  if (sg == 1) {
#pragma unroll
    for (int i = 0; i < 2; ++i)
#pragma unroll
      for (int j = 0; j < 2; ++j)
        red4[i * 2 + j][t] = acc[i][j];
  }
  __syncthreads();

  // both z: sg0 reduces + exp -> ldsT[row_local][col_local]
  if (sg == 0) {
#pragma unroll
    for (int i = 0; i < 2; ++i)
#pragma unroll
      for (int j = 0; j < 2; ++j) {
        const f32x4 o = red4[i * 2 + j][t];
        const f32x4 s = acc[i][j] + o;
#pragma unroll
        for (int r = 0; r < 4; ++r) {
          const int rl = wr * 32 + i * 16 + (l >> 4) * 4 + r;
          const int cl = wc * 32 + j * 16 + (l & 15);
          ldsT[rl][cl] = __expf(2.0f * s[r]);
        }
      }
  }
  __syncthreads();

  if (z == 0) {
    // EQT4[tg][r][u]: tg=(mb*64+row_l)>>2, r=row_l&3, u=nb*64+u_l. Coalesced.
    const int u_l = tid & 63;
#pragma unroll
    for (int it = 0; it < 8; ++it) {
      const int row_l = it * 8 + (tid >> 6);
      const int tg = (mb * 64 + row_l) >> 2;
      EQT4[(size_t)tg * 2048 + (size_t)(row_l & 3) * 512 + nb * 64 + u_l] =
          ldsT[row_l][u_l];
    }
  } else {
    const int b  = (mb * 64) >> 8;
    const int v0 = (mb * 64) & 255;
    const int vl = tid & 63;
#pragma unroll
    for (int it = 0; it < 8; ++it) {
      const int ul = it * 8 + (tid >> 6);
      EKT[(size_t)b * 131072 + (size_t)(nb * 64 + ul) * 256 + v0 + vl] = ldsT[vl][ul];
    }
  }
#undef STAGE
}

// ---------------------------------------------------------------------------
// bah_attn v13: main loop with SCALAR-PATH eq/scale (s_load via readfirstlane
// + block-scalar EQT4 base): inner-loop LDS traffic = ek reads only; eq/ss
// LDS arrays, staging, and the prologue barrier removed.
// ---------------------------------------------------------------------------
__global__ __launch_bounds__(1024) void bah_attn(
    const float* __restrict__ EQT4, const float* __restrict__ EKT,
    const float* __restrict__ value, const int* __restrict__ mask,
    const float* __restrict__ scale,
    float* __restrict__ ctx_out, float* __restrict__ attn_out)
{
  const int blk = blockIdx.x;
  const int b  = (blk & 7) >> 1;
  const int tg = (blk >> 3) + ((blk & 1) << 5);
  const int tq0 = tg * 4;
  const int bq  = b * 256 + tq0;

  const int tid = threadIdx.x;
  const int v4  = tid & 63;
  const int uq  = tid >> 6;
  const int w   = tid >> 6;
  const int l   = tid & 63;

  __shared__ float wredM[4][4];
  __shared__ float wredS[4][4];
  __shared__ float sumS_lds;
  __shared__ float atT[256][4];
  __shared__ __align__(16) char uA[131072];
  float* const ubufF = (float*)uA;
  float* const partF = (float*)uA;
  float* const ctxpF = (float*)(uA + 65536);

  const float* __restrict__ ekb = EKT + (size_t)b * (512 * 256);
  // block-scalar eq base (transposed-packed): EQT4[tg_glob][r][u]
  const float* __restrict__ eqt = EQT4 + (size_t)(b * 64 + tg) * 2048;

  const int u0 = uq * 32;
  const int u0s = __builtin_amdgcn_readfirstlane(uq) * 32;  // wave-scalar
  float* const wbase = ubufF + uq * 2048;

  const int r   = w & 3;
  const int vg  = w >> 2;
  const int v   = vg * 64 + l;

#define STAGEW(bufp, s)                                                       \
  do {                                                                        \
    _Pragma("unroll")                                                         \
    for (int c_ = 0; c_ < 4; ++c_)                                            \
      gl_lds16(ekb + (size_t)(u0 + (s) * 4 + c_) * 256 + l * 4,               \
               wbase + (bufp) * 1024 + c_ * 256);                             \
  } while (0)

  STAGEW(0, 0);

  const bool mok = (mask[b * 256 + v] != 0);

  // sumS by wave 0 from global scale (no LDS staging)
  if (w == 0) {
    float s = 0.f;
#pragma unroll
    for (int j = 0; j < 8; ++j) s += scale[l + 64 * j];
#pragma unroll
    for (int off = 32; off; off >>= 1) s += __shfl_xor(s, off);
    if (l == 0) sumS_lds = s;
  }

  // ---- main loop: 8 rounds x 2 u-pairs; eq/ss via scalar loads ----
  f2 accp[4][2] = {};
  int bufi = 0;
#pragma unroll 1
  for (int s = 0; s < 8; ++s) {
    if (s < 7) {
      STAGEW(bufi ^ 1, s + 1);
      asm volatile("s_waitcnt vmcnt(4)" ::: "memory");
    } else {
      asm volatile("s_waitcnt vmcnt(0)" ::: "memory");
    }
    __builtin_amdgcn_sched_barrier(0);
    const float* bp = wbase + bufi * 1024;

    // wave-scalar loads: 4 eq-rows (4 u's each) + 4 scales -> SGPRs
    const float* ep = eqt + u0s + s * 4;
    f4 eqr[4];
    eqr[0] = *reinterpret_cast<const f4*>(ep);
    eqr[1] = *reinterpret_cast<const f4*>(ep + 512);
    eqr[2] = *reinterpret_cast<const f4*>(ep + 1024);
    eqr[3] = *reinterpret_cast<const f4*>(ep + 1536);
    const f4 sv = *reinterpret_cast<const f4*>(scale + u0s + s * 4);

#pragma unroll
    for (int cp = 0; cp < 2; ++cp) {
      const f4 ekA4 = *reinterpret_cast<const f4*>(bp + (2 * cp) * 256 + v4 * 4);
      const f4 ekB4 = *reinterpret_cast<const f4*>(bp + (2 * cp + 1) * 256 + v4 * 4);
      const f2 ekA[2] = {{ekA4[0], ekA4[1]}, {ekA4[2], ekA4[3]}};
      const f2 ekB[2] = {{ekB4[0], ekB4[1]}, {ekB4[2], ekB4[3]}};
      const float sA = sv[2 * cp];
      const float sB = sv[2 * cp + 1];
      const f2 sA2 = {sA, sA};
      const f2 sB2 = {sB, sB};
      const f2 one2 = {1.0f, 1.0f};
#pragma unroll
      for (int i = 0; i < 4; ++i) {
        const float ea = eqr[i][2 * cp];
        const float eb = eqr[i][2 * cp + 1];
        const f2 eA2 = {ea, ea};
        const f2 eB2 = {eb, eb};
#pragma unroll
        for (int jh = 0; jh < 2; ++jh) {
          const f2 dA  = __builtin_elementwise_fma(eA2, ekA[jh], one2);
          const f2 dB  = __builtin_elementwise_fma(eB2, ekB[jh], one2);
          const f2 num = __builtin_elementwise_fma(sA2, dB, sB2 * dA);
          const f2 P   = dA * dB;
          f2 r_;
          r_[0] = __builtin_amdgcn_rcpf(P[0]);
          r_[1] = __builtin_amdgcn_rcpf(P[1]);
          accp[i][jh] = __builtin_elementwise_fma(num, r_, accp[i][jh]);
        }
      }
    }
    bufi ^= 1;
  }

  // ---- Phase A: in-place partials (own wave buffer) ----
#pragma unroll
  for (int i = 0; i < 4; ++i) {
    const f4 a4 = {accp[i][0][0], accp[i][0][1], accp[i][1][0], accp[i][1][1]};
    *reinterpret_cast<f4*>(partF + uq * 2048 + i * 256 + v4 * 4) = a4;
  }
  __syncthreads();

  // ---- Phase B ----
  float sc, ex;
  {
    float p = 0.f;
#pragma unroll
    for (int u2 = 0; u2 < 16; ++u2) p += partF[u2 * 2048 + r * 256 + v];
    sc = mok ? (sumS_lds - 2.0f * p) : NEG_INF;
    float m = sc;
#pragma unroll
    for (int off = 32; off; off >>= 1) m = fmaxf(m, __shfl_xor(m, off));
    if (l == 0) wredM[r][vg] = m;
  }
  __syncthreads();

  // ---- Phase C ----
  {
    const float m = fmaxf(fmaxf(wredM[r][0], wredM[r][1]),
                          fmaxf(wredM[r][2], wredM[r][3]));
    ex = __expf(sc - m);
    float sm = ex;
#pragma unroll
    for (int off = 32; off; off >>= 1) sm += __shfl_xor(sm, off);
    if (l == 0) wredS[r][vg] = sm;
  }
  __syncthreads();

  // ---- Phase D ----
  {
    const float denom = (wredS[r][0] + wredS[r][1]) + (wredS[r][2] + wredS[r][3]);
    const float a = ex * __builtin_amdgcn_rcpf(denom);
    atT[v][r] = a;
    attn_out[(size_t)(bq + r) * 256 + v] = a;
  }
  __syncthreads();

  // ---- Phase E ----
  const int vc8 = w & 7;
  const int dh  = w >> 3;
  const float* __restrict__ vb = value + (size_t)b * (256 * 512) + dh * 256;
  f4 g0 = {0,0,0,0}, g1 = {0,0,0,0}, g2 = {0,0,0,0}, g3 = {0,0,0,0};
#pragma unroll 4
  for (int v2 = 0; v2 < 32; ++v2) {
    const int vv = vc8 * 32 + v2;
    const f4 a4 = *reinterpret_cast<const f4*>(&atT[vv][0]);
    const f4 x  = *reinterpret_cast<const f4*>(&vb[(size_t)vv * 512 + l * 4]);
    g0 += a4[0] * x;
    g1 += a4[1] * x;
    g2 += a4[2] * x;
    g3 += a4[3] * x;
  }
  {
    float* const cp = ctxpF + vc8 * 2048 + dh * 256 + l * 4;
    *reinterpret_cast<f4*>(cp + 0 * 512) = g0;
    *reinterpret_cast<f4*>(cp + 1 * 512) = g1;
    *reinterpret_cast<f4*>(cp + 2 * 512) = g2;
    *reinterpret_cast<f4*>(cp + 3 * 512) = g3;
  }
  __syncthreads();

  // ---- Phase F ----
  {
    const int row = tid >> 8;
    const int d2  = (tid & 255) * 2;
    f2 s = {0.f, 0.f};
#pragma unroll
    for (int vc = 0; vc < 8; ++vc)
      s += *reinterpret_cast<const f2*>(ctxpF + vc * 2048 + row * 512 + d2);
    *reinterpret_cast<f2*>(&ctx_out[(size_t)(bq + row) * 512 + d2]) = s;
  }
#undef STAGEW
}

// ---------------------------------------------------------------------------
extern "C" void kernel_launch(void* const* d_in, const int* in_sizes, int n_in,
                              void* d_out, int out_size, void* d_ws, size_t ws_size,
                              hipStream_t stream) {
  const float* query = (const float*)d_in[0];
  const float* value = (const float*)d_in[1];
  const int*   mask  = (const int*)d_in[2];
  const float* W1    = (const float*)d_in[3];
  const float* W2    = (const float*)d_in[4];
  const float* scale = (const float*)d_in[5];

  char* ws = (char*)d_ws;
  float* EQT4 = (float*)(ws);                        // 2 MB [256 tg][4 r][512 u]
  float* EKT  = (float*)(ws + (2u << 20));           // 2 MB
  unsigned short* Ahi = (unsigned short*)(ws + (4u << 20));   // 2 MB
  unsigned short* Alo = (unsigned short*)(ws + (6u << 20));   // 2 MB
  unsigned short* Whi = (unsigned short*)(ws + (8u << 20));   // 1 MB
  unsigned short* Wlo = (unsigned short*)(ws + (9u << 20));   // 1 MB

  float* ctx  = (float*)d_out;
  float* attn = ctx + 4 * 256 * 512;

  conv_aw<<<dim3(576), 256, 0, stream>>>(query, value, W1, W2, Ahi, Alo, Whi, Wlo);
  projmm<<<dim3(8, 16, 2), 512, 0, stream>>>(Ahi, Alo, Whi, Wlo, EQT4, EKT);
  bah_attn<<<dim3(256), 1024, 0, stream>>>(EQT4, EKT, value, mask, scale, ctx, attn);
}